// Round 1
// 166.505 us; speedup vs baseline: 1.0322x; 1.0322x over previous
//
#include <hip/hip_runtime.h>
#include <math.h>

#define BATCH 16384
#define LBL   512
#define HID   768
#define TR    128

typedef unsigned long long u64;
typedef unsigned short ushort_t;
typedef __attribute__((ext_vector_type(8))) short short8;
typedef __attribute__((ext_vector_type(4))) float f32x4;

__device__ __forceinline__ ushort_t f2bf(float f){
  unsigned u = __builtin_bit_cast(unsigned, f);
  u += 0x7FFFu + ((u >> 16) & 1u);
  return (ushort_t)(u >> 16);
}
__device__ __forceinline__ float softplusf(float x){
  return fmaxf(x, 0.0f) + log1pf(expf(-fabsf(x)));
}
__device__ __forceinline__ void gload_lds16(const void* g, void* l){
  __builtin_amdgcn_global_load_lds((const __attribute__((address_space(1))) void*)g,
                                   (__attribute__((address_space(3))) void*)l, 16, 0, 0);
}

// ============ k1: M = W0a@Wt, Q = W0b@Wl (swizzled bf16), W1->bf16, KV, zero out ============
// Swizzle: element (n, k) of a [128 n][768 k] B-matrix at ((k>>3)<<10) + (n<<3) + (k&7);
// chunk kc (64 k) = contiguous 16 KB at elem offset kc*8192 -> global_load_lds ready.
__global__ __launch_bounds__(256) void k1(
    const float* __restrict__ W0, const float* __restrict__ Wt, const float* __restrict__ Wl,
    const float* __restrict__ bt, const float* __restrict__ bl, const float* __restrict__ b0,
    const float* __restrict__ W1,
    ushort_t* __restrict__ Msw, ushort_t* __restrict__ Qsw, ushort_t* __restrict__ W1B,
    float* __restrict__ KV, float* __restrict__ out){
  __shared__ float sw[TR];
  int bi = blockIdx.x, t = threadIdx.x;
  if (bi < 256){
    int i = bi & 127;
    int isQ = bi >> 7;
    const float* src = isQ ? Wl : Wt;
    ushort_t* dst = isQ ? Qsw : Msw;
    if (t < TR) sw[t] = W0[(size_t)i*256 + isQ*128 + t];
    if (!isQ && t < 128) W1B[i*128 + t] = f2bf(W1[i*128 + t]);
    __syncthreads();
    int c = t;
    float a0 = 0.f, a1 = 0.f, a2 = 0.f;
    #pragma unroll 8
    for (int a = 0; a < 128; a++){
      float w = sw[a];
      const float* r = src + (size_t)a*HID;
      a0 = fmaf(w, r[c], a0);
      a1 = fmaf(w, r[c+256], a1);
      a2 = fmaf(w, r[c+512], a2);
    }
    int c7 = c & 7;
    dst[(((c      )>>3)<<10) + (i<<3) + c7] = f2bf(a0);
    dst[(((c + 256)>>3)<<10) + (i<<3) + c7] = f2bf(a1);
    dst[(((c + 512)>>3)<<10) + (i<<3) + c7] = f2bf(a2);
  } else {
    if (t < TR){
      float s = b0[t];
      const float* r = W0 + (size_t)t*256;
      for (int a = 0; a < 128; a++) s = fmaf(r[a], bt[a], s);
      for (int a = 0; a < 128; a++) s = fmaf(r[128+a], bl[a], s);
      KV[t] = s;
    }
    if (t == 0) out[0] = 0.f;
  }
}

// 32-row x 128-col tile GEMM, K=768. B pre-swizzled. A fp32 rows -> bf16 LDS.
// As_: [2][32][80] ushort; Bs_: [2][8192] ushort.
__device__ __forceinline__ void gemm768_32(const float* ap, const ushort_t* Bsw,
                                           ushort_t* As_, ushort_t* Bs_,
                                           int tid, int wave, int m, int q,
                                           f32x4 acc[2][2]){
  float4 ra0 = *(const float4*)ap;
  float4 ra1 = *(const float4*)(ap + 4);
  {
    const char* gb = (const char*)Bsw;
    char* lb = (char*)Bs_;
    #pragma unroll
    for (int p = 0; p < 4; p++)
      gload_lds16(gb + p*4096 + tid*16, lb + p*4096 + tid*16);
  }
  #pragma unroll
  for (int rt = 0; rt < 2; rt++)
    #pragma unroll
    for (int ct = 0; ct < 2; ct++)
      acc[rt][ct] = (f32x4){0.f,0.f,0.f,0.f};

  for (int c = 0; c < 12; c++){
    int buf = c & 1;
    short8 av;
    av[0] = (short)f2bf(ra0.x); av[1] = (short)f2bf(ra0.y);
    av[2] = (short)f2bf(ra0.z); av[3] = (short)f2bf(ra0.w);
    av[4] = (short)f2bf(ra1.x); av[5] = (short)f2bf(ra1.y);
    av[6] = (short)f2bf(ra1.z); av[7] = (short)f2bf(ra1.w);
    *(short8*)(As_ + (size_t)(buf*32 + (tid >> 3))*80 + (tid & 7)*8) = av;
    __syncthreads();
    if (c < 11){
      ra0 = *(const float4*)(ap + (c+1)*64);
      ra1 = *(const float4*)(ap + (c+1)*64 + 4);
      const char* gb = (const char*)Bsw + (size_t)(c+1)*16384;
      char* lb = (char*)(Bs_ + (buf^1)*8192);
      #pragma unroll
      for (int p = 0; p < 4; p++)
        gload_lds16(gb + p*4096 + tid*16, lb + p*4096 + tid*16);
    }
    #pragma unroll
    for (int kcc = 0; kcc < 2; kcc++){
      short8 bfr[2];
      #pragma unroll
      for (int ct = 0; ct < 2; ct++)
        bfr[ct] = *(const short8*)(Bs_ + buf*8192 + (kcc*4 + q)*1024 + (wave*32 + ct*16 + m)*8);
      #pragma unroll
      for (int rt = 0; rt < 2; rt++){
        short8 a = *(const short8*)(As_ + (size_t)(buf*32 + rt*16 + m)*80 + kcc*32 + q*8);
        #pragma unroll
        for (int ct = 0; ct < 2; ct++)
          acc[rt][ct] = __builtin_amdgcn_mfma_f32_16x16x32_bf16(a, bfr[ct], acc[rt][ct], 0, 0, 0);
      }
    }
  }
}

// ============ k2: G = labe @ Q^T only (16 blocks) ============
__global__ __launch_bounds__(256) void k2(
    const float* __restrict__ labe, const ushort_t* __restrict__ Qsw,
    ushort_t* __restrict__ Gt){
  __shared__ __align__(16) char uni[43008];
  int bi = blockIdx.x, tid = threadIdx.x;
  int lane = tid & 63, wave = tid >> 6;
  int m = lane & 15, q = lane >> 4;
  ushort_t* Bs_ = (ushort_t*)uni;
  ushort_t* As_ = (ushort_t*)(uni + 32768);

  int l0 = bi * 32;
  int arow = tid >> 3, ak = (tid & 7) * 8;
  f32x4 accG[2][2];
  gemm768_32(labe + (size_t)(l0 + arow)*HID + ak, Qsw, As_, Bs_, tid, wave, m, q, accG);
  __syncthreads();
  ushort_t (*GTs)[40] = (ushort_t(*)[40])uni;   // [128][40]
  #pragma unroll
  for (int rt = 0; rt < 2; rt++)
    #pragma unroll
    for (int ct = 0; ct < 2; ct++){
      int col = wave*32 + ct*16 + m;
      #pragma unroll
      for (int r = 0; r < 4; r++)
        GTs[col][rt*16 + q*4 + r] = f2bf(accG[rt][ct][r]);
    }
  __syncthreads();
  int gi = tid >> 1, half = tid & 1;
  ushort_t* dstp = Gt + (size_t)gi*LBL + l0 + half*16;
  *(short8*)(dstp)     = *(const short8*)&GTs[gi][half*16];
  *(short8*)(dstp + 8) = *(const short8*)&GTs[gi][half*16 + 8];
}

// ============ k3: 64-row U-GEMM (32 pos + 32 perm neg) + inline bitpack + V + h0 + h1 + score ==
// 512 blocks x 512 thr (8 waves), 32 samples/block. Wave w owns output cols w*16..w*16+15.
// LDS: uni 51200 (GEMM: Bs 32768 + As [2][64][72] 18432; phase-C overlay: h0s [64][136] 17408 +
//      sred [64][129]f 33024 = 50432) + bitsS 2560 + invs 128 -> 2 blocks/CU (grid-capped),
//      16 waves/CU vs old 8.
// tgt bitpack fused here: loads issued in prologue, ballots consumed at GEMM iter c==8
// (HBM latency hidden under ~15us of U-GEMM); barriers c=9..11 publish bitsS before V phase.
__global__ __launch_bounds__(512, 4) void k3(const float* __restrict__ T, const ushort_t* __restrict__ Msw,
                                          const float* __restrict__ KV, const ushort_t* __restrict__ Gt,
                                          const int* __restrict__ tgt,
                                          const int* __restrict__ perm, const ushort_t* __restrict__ W1b,
                                          const float* __restrict__ b1, const float* __restrict__ W2,
                                          const float* __restrict__ b2, float* __restrict__ out){
  __shared__ __align__(16) char uni[51200];
  __shared__ __align__(16) u64 bitsS[32*10];   // 80B pitch per row
  __shared__ float invs[32];

  int tid = threadIdx.x;
  int lane = tid & 63, wave = tid >> 6;        // wave 0..7
  int m = lane & 15, q = lane >> 4;
  int r0 = blockIdx.x * 32;
  ushort_t* Bs_ = (ushort_t*)uni;              // [2][8192]
  ushort_t* As_ = (ushort_t*)(uni + 32768);    // [2][64][72]

  // ---- GEMM A rows: 0..31 = text[r0+i], 32..63 = text[perm[r0+i]] ----
  int ar = tid >> 3, ak = (tid & 7) * 8;       // ar 0..63
  int arow = (ar < 32) ? (r0 + ar) : perm[r0 + ar - 32];
  const float* app = T + (size_t)arow*HID + ak;

  float4 a0 = *(const float4*)(app);
  float4 a1 = *(const float4*)(app + 4);
  {
    const char* gb = (const char*)Msw;
    char* lb = (char*)Bs_;
    gload_lds16(gb + tid*16,        lb + tid*16);
    gload_lds16(gb + 8192 + tid*16, lb + 8192 + tid*16);
  }
  // ---- issue tgt loads for this block's 32 rows (wave w: rows w*4..w*4+3) ----
  int v[4][8];
  #pragma unroll
  for (int rr = 0; rr < 4; rr++){
    const int* rp = tgt + (size_t)(r0 + wave*4 + rr)*LBL;
    #pragma unroll
    for (int cc = 0; cc < 8; cc++) v[rr][cc] = rp[cc*64 + lane];
  }

  f32x4 acc[4];
  #pragma unroll
  for (int rt = 0; rt < 4; rt++) acc[rt] = (f32x4){0.f,0.f,0.f,0.f};

  for (int c = 0; c < 12; c++){
    int buf = c & 1;
    short8 av;
    av[0]=(short)f2bf(a0.x); av[1]=(short)f2bf(a0.y); av[2]=(short)f2bf(a0.z); av[3]=(short)f2bf(a0.w);
    av[4]=(short)f2bf(a1.x); av[5]=(short)f2bf(a1.y); av[6]=(short)f2bf(a1.z); av[7]=(short)f2bf(a1.w);
    *(short8*)(As_ + (size_t)(buf*64 + ar)*72 + ak) = av;
    __syncthreads();
    if (c == 8){
      // consume tgt loads: ballot-pack into bitsS + counts (published by barriers c=9..11)
      #pragma unroll
      for (int rr = 0; rr < 4; rr++){
        int row = wave*4 + rr;
        int cnt = 0;
        #pragma unroll
        for (int cc = 0; cc < 8; cc++){
          u64 mm = __ballot(v[rr][cc] != 0);
          if (lane == 0){ ((u64*)((char*)bitsS + row*80))[cc] = mm; cnt += __popcll(mm); }
        }
        if (lane == 0) invs[row] = 1.0f / (float)(cnt < 1 ? 1 : cnt);
      }
    }
    if (c < 11){
      a0 = *(const float4*)(app + (c+1)*64);
      a1 = *(const float4*)(app + (c+1)*64 + 4);
      const char* gb = (const char*)Msw + (size_t)(c+1)*16384;
      char* lb = (char*)(Bs_ + (buf^1)*8192);
      gload_lds16(gb + tid*16,        lb + tid*16);
      gload_lds16(gb + 8192 + tid*16, lb + 8192 + tid*16);
    }
    #pragma unroll
    for (int kcc = 0; kcc < 2; kcc++){
      short8 bfr = *(const short8*)(Bs_ + buf*8192 + (kcc*4 + q)*1024 + (wave*16 + m)*8);
      #pragma unroll
      for (int rt = 0; rt < 4; rt++){
        short8 a = *(const short8*)(As_ + (size_t)(buf*64 + rt*16 + m)*72 + kcc*32 + q*8);
        acc[rt] = __builtin_amdgcn_mfma_f32_16x16x32_bf16(a, bfr, acc[rt], 0, 0, 0);
      }
    }
  }

  // ---- V = mask @ G (K=512), Gt prefetch 2-deep ----
  const unsigned char* bits_b = (const unsigned char*)bitsS;
  f32x4 accV[2] = {{0,0,0,0},{0,0,0,0}};
  const ushort_t* gp = Gt + (size_t)(wave*16 + m)*LBL + q*8;
  short8 bv0 = *(const short8*)(gp);
  short8 bv1 = *(const short8*)(gp + 32);
  for (int c = 0; c < 16; c++){
    short8 bn = bv1;
    if (c < 14) bn = *(const short8*)(gp + (size_t)(c+2)*32);
    #pragma unroll
    for (int rt = 0; rt < 2; rt++){
      unsigned bb = bits_b[(rt*16 + m)*80 + c*4 + q];
      short8 a;
      #pragma unroll
      for (int j = 0; j < 8; j++) a[j] = (short)(((bb >> j) & 1u) ? 0x3F80 : 0);
      accV[rt] = __builtin_amdgcn_mfma_f32_16x16x32_bf16(a, bv0, accV[rt], 0, 0, 0);
    }
    bv0 = bv1; bv1 = bn;
  }

  // ---- h0 both branches -> LDS (overlay on uni; GEMM LDS dead now) ----
  __syncthreads();
  ushort_t (*h0s)[136] = (ushort_t(*)[136])uni;   // [64][136]: rows 0-31 pos, 32-63 neg
  float* sred = (float*)(uni + 17408);            // [64][129] floats
  int col = wave*16 + m;
  float kv = KV[col];
  #pragma unroll
  for (int rt = 0; rt < 2; rt++){
    #pragma unroll
    for (int r = 0; r < 4; r++){
      int rowl = rt*16 + q*4 + r;
      float vv = accV[rt][r] * invs[rowl] + kv;
      h0s[rowl][col]      = f2bf(fmaxf(acc[rt][r]   + vv, 0.f));
      h0s[32 + rowl][col] = f2bf(fmaxf(acc[rt+2][r] + vv, 0.f));
    }
  }
  __syncthreads();

  float w2c = W2[col], b1c = b1[col];
  float b2v = b2[0];
  #pragma unroll
  for (int rt2 = 0; rt2 < 4; rt2++){
    f32x4 accH = {0,0,0,0};
    #pragma unroll
    for (int kc = 0; kc < 4; kc++){
      short8 a = *(const short8*)&h0s[rt2*16 + m][kc*32 + q*8];
      short8 b = *(const short8*)(W1b + (size_t)col*TR + kc*32 + q*8);
      accH = __builtin_amdgcn_mfma_f32_16x16x32_bf16(a, b, accH, 0, 0, 0);
    }
    #pragma unroll
    for (int r = 0; r < 4; r++){
      float sp = w2c * fmaxf(accH[r] + b1c, 0.f);
      sred[(size_t)(rt2*16 + q*4 + r)*129 + col] = sp;
    }
  }
  __syncthreads();

  if (tid < 64){
    float s = b2v;
    #pragma unroll
    for (int n = 0; n < 128; n++) s += sred[(size_t)tid*129 + n];
    float val = (tid < 32) ? softplusf(-s) : softplusf(s);   // rows 0-31 = pos branch
    #pragma unroll
    for (int off = 32; off > 0; off >>= 1) val += __shfl_down(val, off);
    if (tid == 0) atomicAdd(out, val * (1.0f / (float)BATCH));
  }
}

extern "C" void kernel_launch(void* const* d_in, const int* in_sizes, int n_in,
                              void* d_out, int out_size, void* d_ws, size_t ws_size,
                              hipStream_t stream){
  const float* text = (const float*)d_in[0];
  const float* labe = (const float*)d_in[1];
  const int*   tgt  = (const int*)  d_in[2];
  const int*   perm = (const int*)  d_in[3];
  const float* Wt   = (const float*)d_in[4];
  const float* bt   = (const float*)d_in[5];
  const float* Wl   = (const float*)d_in[6];
  const float* bl   = (const float*)d_in[7];
  const float* W0   = (const float*)d_in[8];
  const float* b0   = (const float*)d_in[9];
  const float* W1   = (const float*)d_in[10];
  const float* b1   = (const float*)d_in[11];
  const float* W2   = (const float*)d_in[12];
  const float* b2   = (const float*)d_in[13];

  char* wsb = (char*)d_ws;
  size_t off = 0;
  auto alloc = [&](size_t bytes){
    size_t r = off;
    off += (bytes + 255) & ~(size_t)255;
    return r;
  };
  ushort_t* MSW = (ushort_t*)(wsb + alloc((size_t)TR*HID*2));
  ushort_t* QSW = (ushort_t*)(wsb + alloc((size_t)TR*HID*2));
  ushort_t* GT  = (ushort_t*)(wsb + alloc((size_t)TR*LBL*2));
  ushort_t* W1B = (ushort_t*)(wsb + alloc((size_t)TR*TR*2));
  float*    KV  = (float*)   (wsb + alloc((size_t)TR*4));
  float*    out = (float*)d_out;
  (void)ws_size; (void)in_sizes; (void)n_in; (void)out_size;

  k1<<<257, 256, 0, stream>>>(W0, Wt, Wl, bt, bl, b0, W1, MSW, QSW, W1B, KV, out);
  k2<<<16, 256, 0, stream>>>(labe, QSW, GT);
  k3<<<512, 512, 0, stream>>>(text, MSW, KV, GT, tgt, perm, W1B, b1, W2, b2, out);
}